// Round 8
// baseline (50.112 us; speedup 1.0000x reference)
//
#include <hip/hip_runtime.h>

#define EPSF  1e-7f
#define LOG2E 1.4426950408889634f

typedef short bf16x8 __attribute__((ext_vector_type(8)));
typedef float f32x4  __attribute__((ext_vector_type(4)));

__device__ __forceinline__ short bf_hi(float f) {
    return (short)(__float_as_uint(f) >> 16);        // truncation; residual exact in f32
}
__device__ __forceinline__ float bf_to_f(short h) {
    return __uint_as_float(((unsigned)(unsigned short)h) << 16);
}

template<int CTRL>
__device__ __forceinline__ float dpp_add(float x) {
    int sh = __builtin_amdgcn_update_dpp(0, __float_as_int(x), CTRL, 0xF, 0xF, true);
    return x + __int_as_float(sh);
}
// all-reduce over lane bits 0..3 (16-lane DPP row): xor1,2,7,15 span GF(2)^4. (r2-r7)
__device__ __forceinline__ float row16_allsum(float x) {
    x = dpp_add<0xB1>(x);   // xor 1
    x = dpp_add<0x4E>(x);   // xor 2
    x = dpp_add<0x141>(x);  // xor 7
    x = dpp_add<0x140>(x);  // xor 15
    return x;
}
// all-reduce over lane bits 4,5 — validated primitives (ds_swizzle + shfl).
__device__ __forceinline__ float oquad_allsum(float x) {
    x += __int_as_float(__builtin_amdgcn_ds_swizzle(__float_as_int(x), 0x401F)); // xor16
    x += __shfl_xor(x, 32, 64);                                                  // xor32
    return x;
}

// LDS layout s_x[k][im][od]: KSTR=636 words, IMSTR=20 words.
// 16*636*4 = 40704 B <= 40960 -> 4 blocks/CU (full residency of the 1024-block grid).
// C-store: 4*636 % 32 == 16 -> l4 groups split {0,16} -> 2-way (free, m136).
// Routing ds_read_b128: 636 % 4 == 0 (aligned); start banks 8*(i4&3)+4*o2 -> 8 words/bank.
#define KSTR 636
#define IMSTR 20

// B=8, predict-m=32, K=256, routing-im=32, OD=16, contraction (yx,e)=32.
// Grid: 1024 blocks = 256 (b*32+m) x 4 k-slices of 64. Block: 512 threads (8 waves).
// Phase 1 (16-k chunk): mfma_f32_16x16x32_bf16, 3-term hi/lo split (r5-validated).
// Phase 2: wave routes tiles 2w,2w+1. lane = i4 | (o2<<4): i4 owns im {2i4,2i4+1},
//          o2 owns od {4o2..4o2+3}. Deferred-scale: squash & bb reductions on
//          UNNORMALIZED u, all three oquads issued in parallel; scale folded into g.
__global__ __launch_bounds__(512, 8)
void caps_fused(const float* __restrict__ pc,   // [8,32,32,32,8]
                const float* __restrict__ Wt,   // [8,32,1,2,2,32,16,8]
                const float* __restrict__ bL,   // [1,32,16,16,32]
                float* __restrict__ out)        // [8,32,16,16,16]
{
    const int bid = blockIdx.x;
    const int bm  = bid >> 2;          // b*32 + m
    const int ks  = bid & 3;           // k-slice of 64
    const int om  = bm & 31;

    const int t    = threadIdx.x;
    const int wav  = t >> 6;
    const int lane = t & 63;
    const int l15  = lane & 15;
    const int l4   = lane >> 4;        // 0..3
    const int i4   = l15;              // phase 2: owns im {2*i4, 2*i4+1}
    const int o2   = l4;               // phase 2: owns od {4*o2 .. 4*o2+3}

    // ---- B fragments (W), wave's 4 N-tiles; lane holds k=(l4)*8+j (r5-validated) ----
    bf16x8 wh[4], wl[4];
    {
        const float* wbase = Wt + (size_t)bm * 16384 + (size_t)l4 * 4096 + (size_t)l15 * 8;
        #pragma unroll
        for (int nt = 0; nt < 4; ++nt) {
            const float4* wp = (const float4*)(wbase + (wav * 4 + nt) * 128);
            float4 w0 = wp[0], w1 = wp[1];
            float f[8] = {w0.x, w0.y, w0.z, w0.w, w1.x, w1.y, w1.z, w1.w};
            #pragma unroll
            for (int j = 0; j < 8; ++j) {
                short h = bf_hi(f[j]);
                wh[nt][j] = h;
                wl[nt][j] = bf_hi(f[j] - bf_to_f(h));
            }
        }
    }

    const float* pcb = pc  + (size_t)bm * 8192;   // [k][yx][e] = [256][4][8]
    const float* bLb = bL  + (size_t)om * 8192;   // [k][im]    = [256][32]
    float*       ob  = out + (size_t)bm * 4096;   // [k][od]    = [256][16]

    __shared__ float s_x[16 * KSTR];

    const int k_lo = ks << 6;

    // A-fragment raw loads for chunk 0 (lane l: x_in[k0+l15][l4*8 + 0..8))
    float4 a0, a1;
    {
        const float4* ap = (const float4*)(pcb + (size_t)(k_lo + l15) * 32 + l4 * 8);
        a0 = ap[0]; a1 = ap[1];
    }

    for (int c = 0; c < 4; ++c) {
        const int k0 = k_lo + (c << 4);
        if (c) __syncthreads();                   // prev chunk's routing reads done

        // ---- convert A to bf16 hi/lo ----
        bf16x8 ah, al;
        {
            float f[8] = {a0.x, a0.y, a0.z, a0.w, a1.x, a1.y, a1.z, a1.w};
            #pragma unroll
            for (int j = 0; j < 8; ++j) {
                short h = bf_hi(f[j]);
                ah[j] = h;
                al[j] = bf_hi(f[j] - bf_to_f(h));
            }
        }

        // ---- 4 N-tiles: 3 MFMA each, C -> LDS [k][im][od] ----
        #pragma unroll
        for (int nt = 0; nt < 4; ++nt) {
            f32x4 acc = {0.f, 0.f, 0.f, 0.f};
            acc = __builtin_amdgcn_mfma_f32_16x16x32_bf16(ah, wh[nt], acc, 0, 0, 0);
            acc = __builtin_amdgcn_mfma_f32_16x16x32_bf16(al, wh[nt], acc, 0, 0, 0);
            acc = __builtin_amdgcn_mfma_f32_16x16x32_bf16(ah, wl[nt], acc, 0, 0, 0);
            const int im = wav * 4 + nt;              // C col-block = im, col = od = l15
            #pragma unroll
            for (int q = 0; q < 4; ++q) {
                const int kr = l4 * 4 + q;            // C row = k
                s_x[kr * KSTR + im * IMSTR + l15] = acc[q];
            }
        }

        // ---- prefetch next chunk's A (overlaps routing) ----
        if (c < 3) {
            const float4* ap = (const float4*)(pcb + (size_t)(k0 + 16 + l15) * 32 + l4 * 8);
            a0 = ap[0]; a1 = ap[1];
        }

        // ---- preload routing logits for both tiles ----
        const int ka = k0 + 2 * wav, kb = ka + 1;
        float2 bba = *(const float2*)(bLb + (ka << 5) + 2 * i4);
        float2 bbb = *(const float2*)(bLb + (kb << 5) + 2 * i4);

        __syncthreads();

        // ---- phase 2: route tiles ka, kb ----
        #pragma unroll
        for (int half = 0; half < 2; ++half) {
            const int k  = half ? kb : ka;
            const int kl = 2 * wav + half;
            const float* xp = &s_x[kl * KSTR + i4 * (2 * IMSTR) + 4 * o2];
            const float4 xa = *(const float4*)xp;            // x[2i4  ][4o2..]
            const float4 xb = *(const float4*)(xp + IMSTR);  // x[2i4+1][4o2..]
            // logits kept in log2 domain: e^b == 2^(b*log2e)
            float b0 = (half ? bbb.x : bba.x) * LOG2E;
            float b1 = (half ? bbb.y : bba.y) * LOG2E;

            float g = 0.f, u0 = 0.f, u1 = 0.f, u2 = 0.f, u3 = 0.f;
            #pragma unroll
            for (int r = 0; r < 3; ++r) {
                float e0 = __builtin_exp2f(b0), e1 = __builtin_exp2f(b1);
                float S  = row16_allsum(e0 + e1);            // softmax denom over 32 im
                float inv = __builtin_amdgcn_rcpf(S);

                // unnormalized v (row16 over im); normalization deferred into g
                u0 = row16_allsum(fmaf(e0, xa.x, e1 * xb.x));
                u1 = row16_allsum(fmaf(e0, xa.y, e1 * xb.y));
                u2 = row16_allsum(fmaf(e0, xa.z, e1 * xb.z));
                u3 = row16_allsum(fmaf(e0, xa.w, e1 * xb.w));

                // all od-reductions on u, mutually independent -> overlapping oquads
                float squ = fmaf(u0, u0, fmaf(u1, u1, fmaf(u2, u2, u3 * u3)));
                float du0 = fmaf(xa.x, u0, fmaf(xa.y, u1, fmaf(xa.z, u2, xa.w * u3)));
                float du1 = fmaf(xb.x, u0, fmaf(xb.y, u1, fmaf(xb.z, u2, xb.w * u3)));
                squ = oquad_allsum(squ);
                if (r < 2) { du0 = oquad_allsum(du0); du1 = oquad_allsum(du1); }

                float sq    = squ * inv * inv;               // |v|^2, v = inv*u
                float scale = sq * __builtin_amdgcn_rcpf(1.f + sq) * rsqrtf(sq + EPSF);
                g = inv * scale;                             // v_scaled = g * u

                if (r < 2) {
                    float gl = g * LOG2E;                    // update in log2 domain
                    b0 = fmaf(gl, du0, b0);
                    b1 = fmaf(gl, du1, b1);
                }
            }

            if (i4 == 0)
                *(float4*)(ob + (k << 4) + 4 * o2) =
                    make_float4(u0 * g, u1 * g, u2 * g, u3 * g);
        }
    }
}

extern "C" void kernel_launch(void* const* d_in, const int* in_sizes, int n_in,
                              void* d_out, int out_size, void* d_ws, size_t ws_size,
                              hipStream_t stream)
{
    const float* pc = (const float*)d_in[0];
    const float* Wt = (const float*)d_in[1];
    const float* bL = (const float*)d_in[2];
    float*       o  = (float*)d_out;
    caps_fused<<<dim3(1024), dim3(512), 0, stream>>>(pc, Wt, bL, o);
}

// Round 9
// 45.995 us; speedup vs baseline: 1.0895x; 1.0895x over previous
//
#include <hip/hip_runtime.h>

#define EPSF  1e-7f
#define LOG2E 1.4426950408889634f

typedef short bf16x8 __attribute__((ext_vector_type(8)));
typedef float f32x4  __attribute__((ext_vector_type(4)));

__device__ __forceinline__ short bf_hi(float f) {
    return (short)(__float_as_uint(f) >> 16);        // truncation; residual exact in f32
}
__device__ __forceinline__ float bf_to_f(short h) {
    return __uint_as_float(((unsigned)(unsigned short)h) << 16);
}

template<int CTRL>
__device__ __forceinline__ float dpp_add(float x) {
    int sh = __builtin_amdgcn_update_dpp(0, __float_as_int(x), CTRL, 0xF, 0xF, true);
    return x + __int_as_float(sh);
}
// all-reduce over lane bits 0..3 (16-lane DPP row): xor1,2,7,15 span GF(2)^4. (r2-r7)
__device__ __forceinline__ float row16_allsum(float x) {
    x = dpp_add<0xB1>(x);   // xor 1
    x = dpp_add<0x4E>(x);   // xor 2
    x = dpp_add<0x141>(x);  // xor 7
    x = dpp_add<0x140>(x);  // xor 15
    return x;
}
// all-reduce over lane bits 4,5 — validated primitives (ds_swizzle + shfl).
__device__ __forceinline__ float oquad_allsum(float x) {
    x += __int_as_float(__builtin_amdgcn_ds_swizzle(__float_as_int(x), 0x401F)); // xor16
    x += __shfl_xor(x, 32, 64);                                                  // xor32
    return x;
}

// LDS layout s_x[k][im][od]: KSTR=636 words, IMSTR=20 words.
// 16*636*4 = 40704 B -> rounds to 40960 -> exactly 4 blocks/CU (full grid residency).
// C-store: 4*636 % 32 == 16 -> 2-way (free, m136). Routing ds_read_b128 aligned,
// start banks 8*(i4&3)+4*o2 -> 8 words/bank, conflict-free (r7: measured 0).
#define KSTR 636
#define IMSTR 20

// B=8, predict-m=32, K=256, routing-im=32, OD=16, contraction (yx,e)=32.
// Grid: 1024 blocks = 256 (b*32+m) x 4 k-slices of 64. Block: 512 threads (8 waves).
// Phase 1 (16-k chunk): mfma_f32_16x16x32_bf16, 3-term hi/lo split (r5-validated).
// Phase 2: wave routes tiles 2w,2w+1. lane = i4 | (o2<<4): i4 owns im {2i4,2i4+1},
//          o2 owns od {4o2..4o2+3}. Deferred-scale routing (r8-validated numerics).
// __launch_bounds__(512,4): r8's (512,8) squeezed VGPR to 32 and SPILLED W to
// scratch (WRITE_SIZE 4->24.6 MB). 128-VGPR budget compiles spill-free at ~40.
__global__ __launch_bounds__(512, 4)
void caps_fused(const float* __restrict__ pc,   // [8,32,32,32,8]
                const float* __restrict__ Wt,   // [8,32,1,2,2,32,16,8]
                const float* __restrict__ bL,   // [1,32,16,16,32]
                float* __restrict__ out)        // [8,32,16,16,16]
{
    const int bid = blockIdx.x;
    const int bm  = bid >> 2;          // b*32 + m
    const int ks  = bid & 3;           // k-slice of 64
    const int om  = bm & 31;

    const int t    = threadIdx.x;
    const int wav  = t >> 6;
    const int lane = t & 63;
    const int l15  = lane & 15;
    const int l4   = lane >> 4;        // 0..3
    const int i4   = l15;              // phase 2: owns im {2*i4, 2*i4+1}
    const int o2   = l4;               // phase 2: owns od {4*o2 .. 4*o2+3}

    // ---- B fragments (W), wave's 4 N-tiles; lane holds k=(l4)*8+j (r5-validated) ----
    bf16x8 wh[4], wl[4];
    {
        const float* wbase = Wt + (size_t)bm * 16384 + (size_t)l4 * 4096 + (size_t)l15 * 8;
        #pragma unroll
        for (int nt = 0; nt < 4; ++nt) {
            const float4* wp = (const float4*)(wbase + (wav * 4 + nt) * 128);
            float4 w0 = wp[0], w1 = wp[1];
            float f[8] = {w0.x, w0.y, w0.z, w0.w, w1.x, w1.y, w1.z, w1.w};
            #pragma unroll
            for (int j = 0; j < 8; ++j) {
                short h = bf_hi(f[j]);
                wh[nt][j] = h;
                wl[nt][j] = bf_hi(f[j] - bf_to_f(h));
            }
        }
    }

    const float* pcb = pc  + (size_t)bm * 8192;   // [k][yx][e] = [256][4][8]
    const float* bLb = bL  + (size_t)om * 8192;   // [k][im]    = [256][32]
    float*       ob  = out + (size_t)bm * 4096;   // [k][od]    = [256][16]

    __shared__ float s_x[16 * KSTR];

    const int k_lo = ks << 6;

    // A-fragment raw loads for chunk 0 (lane l: x_in[k0+l15][l4*8 + 0..8))
    float4 a0, a1;
    {
        const float4* ap = (const float4*)(pcb + (size_t)(k_lo + l15) * 32 + l4 * 8);
        a0 = ap[0]; a1 = ap[1];
    }

    for (int c = 0; c < 4; ++c) {
        const int k0 = k_lo + (c << 4);
        if (c) __syncthreads();                   // prev chunk's routing reads done

        // ---- convert A to bf16 hi/lo ----
        bf16x8 ah, al;
        {
            float f[8] = {a0.x, a0.y, a0.z, a0.w, a1.x, a1.y, a1.z, a1.w};
            #pragma unroll
            for (int j = 0; j < 8; ++j) {
                short h = bf_hi(f[j]);
                ah[j] = h;
                al[j] = bf_hi(f[j] - bf_to_f(h));
            }
        }

        // ---- 4 N-tiles: 3 MFMA each, C -> LDS [k][im][od] ----
        #pragma unroll
        for (int nt = 0; nt < 4; ++nt) {
            f32x4 acc = {0.f, 0.f, 0.f, 0.f};
            acc = __builtin_amdgcn_mfma_f32_16x16x32_bf16(ah, wh[nt], acc, 0, 0, 0);
            acc = __builtin_amdgcn_mfma_f32_16x16x32_bf16(al, wh[nt], acc, 0, 0, 0);
            acc = __builtin_amdgcn_mfma_f32_16x16x32_bf16(ah, wl[nt], acc, 0, 0, 0);
            const int im = wav * 4 + nt;              // C col-block = im, col = od = l15
            #pragma unroll
            for (int q = 0; q < 4; ++q) {
                const int kr = l4 * 4 + q;            // C row = k
                s_x[kr * KSTR + im * IMSTR + l15] = acc[q];
            }
        }

        // ---- prefetch next chunk's A (overlaps routing) ----
        if (c < 3) {
            const float4* ap = (const float4*)(pcb + (size_t)(k0 + 16 + l15) * 32 + l4 * 8);
            a0 = ap[0]; a1 = ap[1];
        }

        // ---- preload routing logits for both tiles ----
        const int ka = k0 + 2 * wav, kb = ka + 1;
        float2 bba = *(const float2*)(bLb + (ka << 5) + 2 * i4);
        float2 bbb = *(const float2*)(bLb + (kb << 5) + 2 * i4);

        __syncthreads();

        // ---- phase 2: route tiles ka, kb ----
        #pragma unroll
        for (int half = 0; half < 2; ++half) {
            const int k  = half ? kb : ka;
            const int kl = 2 * wav + half;
            const float* xp = &s_x[kl * KSTR + i4 * (2 * IMSTR) + 4 * o2];
            const float4 xa = *(const float4*)xp;            // x[2i4  ][4o2..]
            const float4 xb = *(const float4*)(xp + IMSTR);  // x[2i4+1][4o2..]
            // logits kept in log2 domain: e^b == 2^(b*log2e)
            float b0 = (half ? bbb.x : bba.x) * LOG2E;
            float b1 = (half ? bbb.y : bba.y) * LOG2E;

            float g = 0.f, u0 = 0.f, u1 = 0.f, u2 = 0.f, u3 = 0.f;
            #pragma unroll
            for (int r = 0; r < 3; ++r) {
                float e0 = __builtin_exp2f(b0), e1 = __builtin_exp2f(b1);
                float S  = row16_allsum(e0 + e1);            // softmax denom over 32 im
                float inv = __builtin_amdgcn_rcpf(S);

                // unnormalized v (row16 over im); normalization deferred into g
                u0 = row16_allsum(fmaf(e0, xa.x, e1 * xb.x));
                u1 = row16_allsum(fmaf(e0, xa.y, e1 * xb.y));
                u2 = row16_allsum(fmaf(e0, xa.z, e1 * xb.z));
                u3 = row16_allsum(fmaf(e0, xa.w, e1 * xb.w));

                // all od-reductions on u, mutually independent -> overlapping oquads
                float squ = fmaf(u0, u0, fmaf(u1, u1, fmaf(u2, u2, u3 * u3)));
                float du0 = fmaf(xa.x, u0, fmaf(xa.y, u1, fmaf(xa.z, u2, xa.w * u3)));
                float du1 = fmaf(xb.x, u0, fmaf(xb.y, u1, fmaf(xb.z, u2, xb.w * u3)));
                squ = oquad_allsum(squ);
                if (r < 2) { du0 = oquad_allsum(du0); du1 = oquad_allsum(du1); }

                float sq    = squ * inv * inv;               // |v|^2, v = inv*u
                float scale = sq * __builtin_amdgcn_rcpf(1.f + sq) * rsqrtf(sq + EPSF);
                g = inv * scale;                             // v_scaled = g * u

                if (r < 2) {
                    float gl = g * LOG2E;                    // update in log2 domain
                    b0 = fmaf(gl, du0, b0);
                    b1 = fmaf(gl, du1, b1);
                }
            }

            if (i4 == 0)
                *(float4*)(ob + (k << 4) + 4 * o2) =
                    make_float4(u0 * g, u1 * g, u2 * g, u3 * g);
        }
    }
}

extern "C" void kernel_launch(void* const* d_in, const int* in_sizes, int n_in,
                              void* d_out, int out_size, void* d_ws, size_t ws_size,
                              hipStream_t stream)
{
    const float* pc = (const float*)d_in[0];
    const float* Wt = (const float*)d_in[1];
    const float* bL = (const float*)d_in[2];
    float*       o  = (float*)d_out;
    caps_fused<<<dim3(1024), dim3(512), 0, stream>>>(pc, Wt, bL, o);
}